// Round 9
// baseline (369.902 us; speedup 1.0000x reference)
//
#include <hip/hip_runtime.h>
#include <hip/hip_bf16.h>
#include <math.h>

// Problem constants (fixed by reference)
constexpr int Bz = 2, Sq = 4096, Dm = 768, Hn = 12, Hd = 64;
constexpr int Mrows = Bz * Sq;  // 8192
constexpr int LDQKV = 2304;     // fused QKV output row stride

typedef short bf16x8 __attribute__((ext_vector_type(8)));
typedef short s16x4 __attribute__((ext_vector_type(4)));
typedef float f32x4 __attribute__((ext_vector_type(4)));

__device__ __forceinline__ short f2bf(float f) {
  unsigned u = __builtin_bit_cast(unsigned, f);
  u += 0x7fffu + ((u >> 16) & 1u);  // round-to-nearest-even
  return (short)(u >> 16);
}

__device__ __forceinline__ unsigned cvt_pk_bf16(float a, float b) {
  unsigned r;
  asm("v_cvt_pk_bf16_f32 %0, %1, %2" : "=v"(r) : "v"(a), "v"(b));
  return r;  // lo16 = bf16(a), hi16 = bf16(b)
}

// global -> LDS direct DMA, 16B/lane. LDS dest must be WAVE-UNIFORM base
// (lane i lands at base + i*16); global src is per-lane (pre-swizzled).
typedef const __attribute__((address_space(1))) void* gas_cvp;
typedef __attribute__((address_space(3))) void* las_vp;
__device__ __forceinline__ void gload_lds16(const void* g, void* l) {
  __builtin_amdgcn_global_load_lds((gas_cvp)g, (las_vp)l, 16, 0, 0);
}

// ---------------------------------------------------------------------------
// Weight prep: W[768][768] f32 (x@W layout) -> Wt[z*768 + n][k] bf16 (n=out col)
// ---------------------------------------------------------------------------
__global__ __launch_bounds__(256) void wprep_kernel(
    const float* __restrict__ Wq, const float* __restrict__ Wk,
    const float* __restrict__ Wv, const float* __restrict__ Wo,
    short* __restrict__ Wt) {
  __shared__ short T[64][72];
  const float* W = blockIdx.z == 0 ? Wq : blockIdx.z == 1 ? Wk
                 : blockIdx.z == 2 ? Wv : Wo;
  const int k0 = blockIdx.x * 64, n0 = blockIdx.y * 64;
  const int t = threadIdx.x;
  const int c4 = (t & 15) * 4, r = t >> 4;
#pragma unroll
  for (int i = 0; i < 4; ++i) {
    const int k = r + i * 16;
    const float4 wv = *(const float4*)(W + (size_t)(k0 + k) * 768 + n0 + c4);
    T[c4 + 0][k] = f2bf(wv.x);
    T[c4 + 1][k] = f2bf(wv.y);
    T[c4 + 2][k] = f2bf(wv.z);
    T[c4 + 3][k] = f2bf(wv.w);
  }
  __syncthreads();
  const int cn = t & 7, nn = t >> 3;
#pragma unroll
  for (int i = 0; i < 2; ++i) {
    const int n = nn + i * 32;
    *(bf16x8*)(Wt + ((size_t)blockIdx.z * 768 + n0 + n) * 768 + k0 + cn * 8) =
        *(const bf16x8*)&T[n][cn * 8];
  }
}

__global__ __launch_bounds__(256) void biaspack_kernel(
    const float* __restrict__ bq, const float* __restrict__ bk,
    const float* __restrict__ bv, const float* __restrict__ bo,
    float* __restrict__ dst) {
  const int j = blockIdx.x * 256 + threadIdx.x;  // 0..3071
  dst[j] = j < 768 ? bq[j] : j < 1536 ? bk[j - 768]
         : j < 2304 ? bv[j - 1536] : bo[j - 2304];
}

// ---------------------------------------------------------------------------
// LayerNorm -> bf16 output. One block per row of 768, 256 threads.
// ---------------------------------------------------------------------------
__global__ __launch_bounds__(256) void ln_kernel(
    const float* __restrict__ x, const float* __restrict__ g,
    const float* __restrict__ b, short* __restrict__ xn) {
  const int row = blockIdx.x;
  const int t = threadIdx.x;
  const float* xr = x + (size_t)row * Dm;
  const float v0 = xr[t], v1 = xr[t + 256], v2 = xr[t + 512];
  float s = v0 + v1 + v2;
  float ss = v0 * v0 + v1 * v1 + v2 * v2;
#pragma unroll
  for (int m = 32; m >= 1; m >>= 1) {
    s += __shfl_xor(s, m);
    ss += __shfl_xor(ss, m);
  }
  __shared__ float red[8];
  const int wid = t >> 6, lane = t & 63;
  if (lane == 0) { red[wid] = s; red[4 + wid] = ss; }
  __syncthreads();
  s = red[0] + red[1] + red[2] + red[3];
  ss = red[4] + red[5] + red[6] + red[7];
  const float mu = s * (1.0f / Dm);
  const float var = ss * (1.0f / Dm) - mu * mu;
  const float rstd = rsqrtf(var + 1e-5f);
  short* xo = xn + (size_t)row * Dm;
  xo[t]       = f2bf((v0 - mu) * rstd * g[t]       + b[t]);
  xo[t + 256] = f2bf((v1 - mu) * rstd * g[t + 256] + b[t + 256]);
  xo[t + 512] = f2bf((v2 - mu) * rstd * g[t + 512] + b[t + 512]);
}

// ---------------------------------------------------------------------------
// bf16 MFMA GEMM, 128x128 tile, BK=64, 4 waves (2x2), 64x64 per wave.
// Staging via global_load_lds(16B): linear LDS dest, pre-swizzled global
// source (slot^rg), swizzled b128 reads (involution). m97 structure.
// VTFUSE: n0>=1536 blocks (V of fused QKV) write output transposed into
// vt [B,H,64,S] (short4 runs along S), fusing vtrans.
// ---------------------------------------------------------------------------
template <bool OUT_BF16, bool RESID, bool VTFUSE>
__global__ __launch_bounds__(256) void gemm128_kernel(
    const short* __restrict__ A, int ldA, const short* __restrict__ Bt,
    const float* __restrict__ bias, const float* __restrict__ resid,
    void* __restrict__ C, int ldC, short* __restrict__ vtp) {
  __shared__ short As[128 * 64];
  __shared__ short Bs[128 * 64];
  const int m0 = blockIdx.x * 128, n0 = blockIdx.y * 128;
  const int t = threadIdx.x;
  const int w = t >> 6, l = t & 63;
  const int wm = w >> 1, wn = w & 1;
  const int lr = l & 15, lg = l >> 4;
  const int rg = l >> 3, slot = l & 7;  // staging lane decomposition

  f32x4 acc[4][4] = {};

  for (int kt = 0; kt < 768; kt += 64) {
    __syncthreads();  // prior iteration's frag reads complete
#pragma unroll
    for (int it = 0; it < 4; ++it) {
      const int rowb = it * 32 + w * 8;        // wave-uniform base row
      const int row = rowb + rg;               // this lane's row (row&7 == rg)
      const int kc = kt + ((slot ^ rg) * 8);   // pre-swizzled source col
      gload_lds16(A + (size_t)(m0 + row) * ldA + kc, &As[rowb * 64]);
      gload_lds16(Bt + (size_t)(n0 + row) * 768 + kc, &Bs[rowb * 64]);
    }
    __syncthreads();  // compiler drains vmcnt before s_barrier -> tiles ready
#pragma unroll
    for (int ks = 0; ks < 2; ++ks) {
      bf16x8 af[4], bfr[4];
#pragma unroll
      for (int f = 0; f < 4; ++f) {
        const int ar = wm * 64 + f * 16 + lr;
        af[f] = *(const bf16x8*)&As[ar * 64 + (((ks * 4 + lg) ^ (ar & 7)) * 8)];
        const int br = wn * 64 + f * 16 + lr;
        bfr[f] = *(const bf16x8*)&Bs[br * 64 + (((ks * 4 + lg) ^ (br & 7)) * 8)];
      }
      __builtin_amdgcn_s_setprio(1);
#pragma unroll
      for (int mf = 0; mf < 4; ++mf)
#pragma unroll
        for (int nf = 0; nf < 4; ++nf)
          acc[mf][nf] = __builtin_amdgcn_mfma_f32_16x16x32_bf16(
              af[mf], bfr[nf], acc[mf][nf], 0, 0, 0);
      __builtin_amdgcn_s_setprio(0);
    }
  }

  const int colbase = n0 + wn * 64;
  const int rowbase = m0 + wm * 64;
  const bool vpath = VTFUSE && (n0 >= 1536);
#pragma unroll
  for (int nf = 0; nf < 4; ++nf) {
    const int col = colbase + nf * 16 + lr;
    const float bb = bias[col];
    if (vpath) {
      // V section: write transposed into vt [B,H,64,S]
      const int dcol = col - 1536;              // 0..767
      const int hh = dcol >> 6, dd = dcol & 63;
#pragma unroll
      for (int mf = 0; mf < 4; ++mf) {
        const int row0_ = rowbase + mf * 16 + lg * 4;  // global M row of rr=0
        const int bI = row0_ >> 12;                    // batch
        const int s0 = row0_ & 4095;                   // seq pos
        s16x4 pk;
#pragma unroll
        for (int rr = 0; rr < 4; ++rr) pk[rr] = f2bf(acc[mf][nf][rr] + bb);
        *(s16x4*)(vtp + ((size_t)(bI * Hn + hh) * Hd + dd) * Sq + s0) = pk;
      }
    } else {
#pragma unroll
      for (int mf = 0; mf < 4; ++mf) {
#pragma unroll
        for (int rr = 0; rr < 4; ++rr) {
          const int row = rowbase + mf * 16 + lg * 4 + rr;
          const float vv = acc[mf][nf][rr] + bb;
          if constexpr (OUT_BF16) {
            ((short*)C)[(size_t)row * ldC + col] = f2bf(vv);
          } else {
            ((float*)C)[(size_t)row * ldC + col] =
                vv + resid[(size_t)row * 768 + col];
          }
        }
      }
    }
  }
}

// ---------------------------------------------------------------------------
// Flash attention, bf16 MFMA 16x16x32, SWAPPED QK^T (S^T = K·Q^T).
// Softmax numerics = round-4 verbatim (always-rescale, per-lane psum, lrow,
// shuffle epilogue — known good).
// NEW: double-buffered K/V staged via global_load_lds(16B) with ONE barrier
// per kv-tile (T3 minimum 2-phase): stage t+1 into buf^1 at tile start,
// compute tile t from buf, barrier (vmcnt drains there), swap.
// ---------------------------------------------------------------------------
__global__ __launch_bounds__(256) void attn_mfma_kernel(
    const short* __restrict__ qg, const short* __restrict__ kg,
    const short* __restrict__ vt, short* __restrict__ o) {
  __shared__ short Ks[2][64 * 64];  // [kv][d] swizzled, double-buffered
  __shared__ short Vs[2][64 * 64];  // [d][kv] swizzled, double-buffered
  __shared__ short Ps[4][16 * 64];  // wave-private [q][kv] swizzled
  const int q0 = blockIdx.x * 64;
  const int h = blockIdx.y, b = blockIdx.z;
  const size_t qkbase = ((size_t)b * Sq) * LDQKV + (size_t)h * Hd;
  const size_t vbase = ((size_t)(b * Hn + h) * Hd) * Sq;
  const size_t obase = ((size_t)b * Sq) * Dm + (size_t)h * Hd;
  const int t = threadIdx.x;
  const int w = t >> 6, l = t & 63;
  const int lr = l & 15, lg = l >> 4;
  const int rg = l >> 3, slot = l & 7;  // staging lane decomposition

  // Q fragments (B-operand of swapped QK^T), hoisted
  bf16x8 aq0, aq1;
  {
    const short* qp = qg + qkbase + (size_t)(q0 + w * 16 + lr) * LDQKV + lg * 8;
    aq0 = *(const bf16x8*)qp;
    aq1 = *(const bf16x8*)(qp + 32);
  }

  float mrow = -INFINITY;  // running max for q = lr (log2 domain)
  float lrow = 0.f;        // per-lane PARTIAL denominator for q = lr
  f32x4 oacc[4] = {};      // lane: q = lg*4+r, d = nt*16+lr

  constexpr float SC = 0.18033688011112042f;  // (1/8) * log2(e)

  // stage one 64x64 K tile + V tile into buffer `buf` (2 gload_lds pairs/lane)
  auto stage = [&](int buf, int kt) {
#pragma unroll
    for (int it = 0; it < 2; ++it) {
      const int rowb = it * 32 + w * 8;        // wave-uniform base row
      const int row = rowb + rg;               // row&7 == rg
      const int sc = (slot ^ rg) * 8;          // pre-swizzled source col
      gload_lds16(kg + qkbase + (size_t)(kt + row) * LDQKV + sc,
                  &Ks[buf][rowb * 64]);
      gload_lds16(vt + vbase + (size_t)row * Sq + kt + sc,
                  &Vs[buf][rowb * 64]);
    }
  };

  stage(0, 0);
  __syncthreads();  // tile 0 landed (vmcnt drained at barrier)
  int cur = 0;

  for (int kt = 0; kt < Sq; kt += 64) {
    // issue next tile's DMA into the other buffer; drains at tile-end barrier
    if (kt + 64 < Sq) stage(cur ^ 1, kt + 64);

    // S^T = K Q^T : s[nt][r] = S[kv = nt*16+lg*4+r][q = lr]
    f32x4 s[4];
    __builtin_amdgcn_s_setprio(1);
#pragma unroll
    for (int nt = 0; nt < 4; ++nt) {
      const int jr = nt * 16 + lr;
      const bf16x8 k0 = *(const bf16x8*)&Ks[cur][jr * 64 + ((lg ^ (jr & 7)) * 8)];
      const bf16x8 k1 = *(const bf16x8*)&Ks[cur][jr * 64 + (((4 + lg) ^ (jr & 7)) * 8)];
      f32x4 acc = {};
      acc = __builtin_amdgcn_mfma_f32_16x16x32_bf16(k0, aq0, acc, 0, 0, 0);
      acc = __builtin_amdgcn_mfma_f32_16x16x32_bf16(k1, aq1, acc, 0, 0, 0);
      s[nt] = acc;
    }
    __builtin_amdgcn_s_setprio(0);

    // row max (max3-shaped tree) + 2 cross-lane steps
    const float a0 = fmaxf(fmaxf(s[0][0], s[0][1]), s[0][2]);
    const float a1 = fmaxf(fmaxf(s[0][3], s[1][0]), s[1][1]);
    const float a2 = fmaxf(fmaxf(s[1][2], s[1][3]), s[2][0]);
    const float a3 = fmaxf(fmaxf(s[2][1], s[2][2]), s[2][3]);
    const float a4 = fmaxf(fmaxf(s[3][0], s[3][1]), s[3][2]);
    float tm = fmaxf(fmaxf(fmaxf(a0, a1), fmaxf(a2, a3)), fmaxf(a4, s[3][3]));
    tm = fmaxf(tm, __shfl_xor(tm, 16));
    tm = fmaxf(tm, __shfl_xor(tm, 32));

    // online softmax (always rescale — known-good numerics)
    const float mn = fmaxf(mrow, tm * SC);
    const float esc = __builtin_amdgcn_exp2f(mrow - mn);
    mrow = mn;
    const float negmn = -mn;
    float psum = 0.f;
#pragma unroll
    for (int nt = 0; nt < 4; ++nt)
#pragma unroll
      for (int r = 0; r < 4; ++r) {
        const float p = __builtin_amdgcn_exp2f(fmaf(s[nt][r], SC, negmn));
        s[nt][r] = p;
        psum += p;
      }
    lrow = lrow * esc + psum;  // partial over this lane's kv quarter

    // broadcast esc to oacc rows (q = lg*4+r lives at lane lg*4+r)
    float escq[4];
#pragma unroll
    for (int r = 0; r < 4; ++r) escq[r] = __shfl(esc, lg * 4 + r);
#pragma unroll
    for (int nt = 0; nt < 4; ++nt)
#pragma unroll
      for (int r = 0; r < 4; ++r) oacc[nt][r] *= escq[r];

    // P pack: r-pairs are kv-adjacent -> cvt_pk + one b64 write per nt
#pragma unroll
    for (int nt = 0; nt < 4; ++nt) {
      uint2 pk;
      pk.x = cvt_pk_bf16(s[nt][0], s[nt][1]);
      pk.y = cvt_pk_bf16(s[nt][2], s[nt][3]);
      const int pslot = (nt * 2 + (lg >> 1)) ^ (lr & 7);
      *(uint2*)&Ps[w][lr * 64 + pslot * 8 + (lg & 1) * 4] = pk;
    }
    const bf16x8 ap0 = *(const bf16x8*)&Ps[w][lr * 64 + ((lg ^ (lr & 7)) * 8)];
    const bf16x8 ap1 = *(const bf16x8*)&Ps[w][lr * 64 + (((4 + lg) ^ (lr & 7)) * 8)];

    // O += P V
    __builtin_amdgcn_s_setprio(1);
#pragma unroll
    for (int nt = 0; nt < 4; ++nt) {
      const int dr = nt * 16 + lr;
      const bf16x8 b0 = *(const bf16x8*)&Vs[cur][dr * 64 + ((lg ^ (dr & 7)) * 8)];
      const bf16x8 b1 = *(const bf16x8*)&Vs[cur][dr * 64 + (((4 + lg) ^ (dr & 7)) * 8)];
      oacc[nt] = __builtin_amdgcn_mfma_f32_16x16x32_bf16(ap0, b0, oacc[nt], 0, 0, 0);
      oacc[nt] = __builtin_amdgcn_mfma_f32_16x16x32_bf16(ap1, b1, oacc[nt], 0, 0, 0);
    }
    __builtin_amdgcn_s_setprio(0);

    __syncthreads();  // all reads of buf done; next tile's DMA drained here
    cur ^= 1;
  }

  // epilogue: reduce l across kv-quarter lanes, broadcast inv, write bf16
  float lt = lrow + __shfl_xor(lrow, 16);
  lt += __shfl_xor(lt, 32);
  const float inv = 1.0f / lt;  // valid per lane for q = lr
  float invq[4];
#pragma unroll
  for (int r = 0; r < 4; ++r) invq[r] = __shfl(inv, lg * 4 + r);
#pragma unroll
  for (int r = 0; r < 4; ++r) {
    short* orow = o + obase + (size_t)(q0 + w * 16 + lg * 4 + r) * Dm;
#pragma unroll
    for (int nt = 0; nt < 4; ++nt)
      orow[nt * 16 + lr] = f2bf(oacc[nt][r] * invq[r]);
  }
}

// ---------------------------------------------------------------------------
extern "C" void kernel_launch(void* const* d_in, const int* in_sizes, int n_in,
                              void* d_out, int out_size, void* d_ws, size_t ws_size,
                              hipStream_t stream) {
  (void)in_sizes; (void)n_in; (void)out_size; (void)ws_size;
  const float* x  = (const float*)d_in[0];
  const float* Wq = (const float*)d_in[1];
  const float* bq = (const float*)d_in[2];
  const float* Wk = (const float*)d_in[3];
  const float* bk = (const float*)d_in[4];
  const float* Wv = (const float*)d_in[5];
  const float* bv = (const float*)d_in[6];
  const float* Wo = (const float*)d_in[7];
  const float* bo = (const float*)d_in[8];
  const float* lg = (const float*)d_in[9];
  const float* lb = (const float*)d_in[10];
  float* out = (float*)d_out;

  const size_t n = (size_t)Mrows * Dm;
  short* ws16 = (short*)d_ws;
  short* xn   = ws16;                             // bf16 LN out      [M][768]
  short* qkv  = xn + n;                           // bf16 QK(+V slot) [M][2304]
  short* vt   = qkv + (size_t)Mrows * LDQKV;      // bf16 V^T         [B,H,64,S]
  short* ab   = vt + n;                           // bf16 attn out    [M][768]
  short* Wt   = ab + n;                           // bf16 weights^T   [3072][768]
  float* ball = (float*)(Wt + (size_t)3072 * 768);  // f32 bias      [3072]

  wprep_kernel<<<dim3(12, 12, 4), 256, 0, stream>>>(Wq, Wk, Wv, Wo, Wt);
  biaspack_kernel<<<12, 256, 0, stream>>>(bq, bk, bv, bo, ball);
  ln_kernel<<<Mrows, 256, 0, stream>>>(x, lg, lb, xn);
  gemm128_kernel<true, false, true><<<dim3(Mrows / 128, LDQKV / 128), 256, 0, stream>>>(
      xn, Dm, Wt, ball, nullptr, qkv, LDQKV, vt);
  attn_mfma_kernel<<<dim3(Sq / 64, Hn, Bz), 256, 0, stream>>>(qkv, qkv + 768, vt, ab);
  gemm128_kernel<false, true, false><<<dim3(Mrows / 128, Dm / 128), 256, 0, stream>>>(
      ab, Dm, Wt + (size_t)2304 * 768, ball + 2304, x, out, Dm, nullptr);
}

// Round 13
// 355.493 us; speedup vs baseline: 1.0405x; 1.0405x over previous
//
#include <hip/hip_runtime.h>
#include <hip/hip_bf16.h>
#include <math.h>

// Problem constants (fixed by reference)
constexpr int Bz = 2, Sq = 4096, Dm = 768, Hn = 12, Hd = 64;
constexpr int Mrows = Bz * Sq;  // 8192
constexpr int LDQKV = 2304;     // fused QKV output row stride

typedef short bf16x8 __attribute__((ext_vector_type(8)));
typedef short s16x4 __attribute__((ext_vector_type(4)));
typedef float f32x4 __attribute__((ext_vector_type(4)));

__device__ __forceinline__ short f2bf(float f) {
  unsigned u = __builtin_bit_cast(unsigned, f);
  u += 0x7fffu + ((u >> 16) & 1u);  // round-to-nearest-even
  return (short)(u >> 16);
}

__device__ __forceinline__ unsigned cvt_pk_bf16(float a, float b) {
  unsigned r;
  asm("v_cvt_pk_bf16_f32 %0, %1, %2" : "=v"(r) : "v"(a), "v"(b));
  return r;  // lo16 = bf16(a), hi16 = bf16(b)
}

// global -> LDS direct DMA, 16B/lane. LDS dest must be WAVE-UNIFORM base
// (lane i lands at base + i*16); global src is per-lane (pre-swizzled).
typedef const __attribute__((address_space(1))) void* gas_cvp;
typedef __attribute__((address_space(3))) void* las_vp;
__device__ __forceinline__ void gload_lds16(const void* g, void* l) {
  __builtin_amdgcn_global_load_lds((gas_cvp)g, (las_vp)l, 16, 0, 0);
}

// ---------------------------------------------------------------------------
// Weight prep: W[768][768] f32 (x@W layout) -> Wt[z*768 + n][k] bf16 (n=out col)
// ---------------------------------------------------------------------------
__global__ __launch_bounds__(256) void wprep_kernel(
    const float* __restrict__ Wq, const float* __restrict__ Wk,
    const float* __restrict__ Wv, const float* __restrict__ Wo,
    short* __restrict__ Wt) {
  __shared__ short T[64][72];
  const float* W = blockIdx.z == 0 ? Wq : blockIdx.z == 1 ? Wk
                 : blockIdx.z == 2 ? Wv : Wo;
  const int k0 = blockIdx.x * 64, n0 = blockIdx.y * 64;
  const int t = threadIdx.x;
  const int c4 = (t & 15) * 4, r = t >> 4;
#pragma unroll
  for (int i = 0; i < 4; ++i) {
    const int k = r + i * 16;
    const float4 wv = *(const float4*)(W + (size_t)(k0 + k) * 768 + n0 + c4);
    T[c4 + 0][k] = f2bf(wv.x);
    T[c4 + 1][k] = f2bf(wv.y);
    T[c4 + 2][k] = f2bf(wv.z);
    T[c4 + 3][k] = f2bf(wv.w);
  }
  __syncthreads();
  const int cn = t & 7, nn = t >> 3;
#pragma unroll
  for (int i = 0; i < 2; ++i) {
    const int n = nn + i * 32;
    *(bf16x8*)(Wt + ((size_t)blockIdx.z * 768 + n0 + n) * 768 + k0 + cn * 8) =
        *(const bf16x8*)&T[n][cn * 8];
  }
}

__global__ __launch_bounds__(256) void biaspack_kernel(
    const float* __restrict__ bq, const float* __restrict__ bk,
    const float* __restrict__ bv, const float* __restrict__ bo,
    float* __restrict__ dst) {
  const int j = blockIdx.x * 256 + threadIdx.x;  // 0..3071
  dst[j] = j < 768 ? bq[j] : j < 1536 ? bk[j - 768]
         : j < 2304 ? bv[j - 1536] : bo[j - 2304];
}

// ---------------------------------------------------------------------------
// LayerNorm -> bf16 output. One block per row of 768, 256 threads.
// ---------------------------------------------------------------------------
__global__ __launch_bounds__(256) void ln_kernel(
    const float* __restrict__ x, const float* __restrict__ g,
    const float* __restrict__ b, short* __restrict__ xn) {
  const int row = blockIdx.x;
  const int t = threadIdx.x;
  const float* xr = x + (size_t)row * Dm;
  const float v0 = xr[t], v1 = xr[t + 256], v2 = xr[t + 512];
  float s = v0 + v1 + v2;
  float ss = v0 * v0 + v1 * v1 + v2 * v2;
#pragma unroll
  for (int m = 32; m >= 1; m >>= 1) {
    s += __shfl_xor(s, m);
    ss += __shfl_xor(ss, m);
  }
  __shared__ float red[8];
  const int wid = t >> 6, lane = t & 63;
  if (lane == 0) { red[wid] = s; red[4 + wid] = ss; }
  __syncthreads();
  s = red[0] + red[1] + red[2] + red[3];
  ss = red[4] + red[5] + red[6] + red[7];
  const float mu = s * (1.0f / Dm);
  const float var = ss * (1.0f / Dm) - mu * mu;
  const float rstd = rsqrtf(var + 1e-5f);
  short* xo = xn + (size_t)row * Dm;
  xo[t]       = f2bf((v0 - mu) * rstd * g[t]       + b[t]);
  xo[t + 256] = f2bf((v1 - mu) * rstd * g[t + 256] + b[t + 256]);
  xo[t + 512] = f2bf((v2 - mu) * rstd * g[t + 512] + b[t + 512]);
}

// ---------------------------------------------------------------------------
// bf16 MFMA GEMM, 128x128 tile, BK=64, 4 waves (2x2), 64x64 per wave.
// Staging via global_load_lds(16B): linear LDS dest, pre-swizzled global
// source (slot^rg), swizzled b128 reads (involution). m97 structure.
// VTFUSE: n0>=1536 blocks (V of fused QKV) write output transposed into
// vt [B,H,64,S] (short4 runs along S), fusing vtrans.
// ---------------------------------------------------------------------------
template <bool OUT_BF16, bool RESID, bool VTFUSE>
__global__ __launch_bounds__(256) void gemm128_kernel(
    const short* __restrict__ A, int ldA, const short* __restrict__ Bt,
    const float* __restrict__ bias, const float* __restrict__ resid,
    void* __restrict__ C, int ldC, short* __restrict__ vtp) {
  __shared__ short As[128 * 64];
  __shared__ short Bs[128 * 64];
  const int m0 = blockIdx.x * 128, n0 = blockIdx.y * 128;
  const int t = threadIdx.x;
  const int w = t >> 6, l = t & 63;
  const int wm = w >> 1, wn = w & 1;
  const int lr = l & 15, lg = l >> 4;
  const int rg = l >> 3, slot = l & 7;  // staging lane decomposition

  f32x4 acc[4][4] = {};

  for (int kt = 0; kt < 768; kt += 64) {
    __syncthreads();  // prior iteration's frag reads complete
#pragma unroll
    for (int it = 0; it < 4; ++it) {
      const int rowb = it * 32 + w * 8;        // wave-uniform base row
      const int row = rowb + rg;               // this lane's row (row&7 == rg)
      const int kc = kt + ((slot ^ rg) * 8);   // pre-swizzled source col
      gload_lds16(A + (size_t)(m0 + row) * ldA + kc, &As[rowb * 64]);
      gload_lds16(Bt + (size_t)(n0 + row) * 768 + kc, &Bs[rowb * 64]);
    }
    __syncthreads();  // compiler drains vmcnt before s_barrier -> tiles ready
#pragma unroll
    for (int ks = 0; ks < 2; ++ks) {
      bf16x8 af[4], bfr[4];
#pragma unroll
      for (int f = 0; f < 4; ++f) {
        const int ar = wm * 64 + f * 16 + lr;
        af[f] = *(const bf16x8*)&As[ar * 64 + (((ks * 4 + lg) ^ (ar & 7)) * 8)];
        const int br = wn * 64 + f * 16 + lr;
        bfr[f] = *(const bf16x8*)&Bs[br * 64 + (((ks * 4 + lg) ^ (br & 7)) * 8)];
      }
      __builtin_amdgcn_s_setprio(1);
#pragma unroll
      for (int mf = 0; mf < 4; ++mf)
#pragma unroll
        for (int nf = 0; nf < 4; ++nf)
          acc[mf][nf] = __builtin_amdgcn_mfma_f32_16x16x32_bf16(
              af[mf], bfr[nf], acc[mf][nf], 0, 0, 0);
      __builtin_amdgcn_s_setprio(0);
    }
  }

  const int colbase = n0 + wn * 64;
  const int rowbase = m0 + wm * 64;
  const bool vpath = VTFUSE && (n0 >= 1536);
#pragma unroll
  for (int nf = 0; nf < 4; ++nf) {
    const int col = colbase + nf * 16 + lr;
    const float bb = bias[col];
    if (vpath) {
      // V section: write transposed into vt [B,H,64,S]
      const int dcol = col - 1536;              // 0..767
      const int hh = dcol >> 6, dd = dcol & 63;
#pragma unroll
      for (int mf = 0; mf < 4; ++mf) {
        const int row0_ = rowbase + mf * 16 + lg * 4;  // global M row of rr=0
        const int bI = row0_ >> 12;                    // batch
        const int s0 = row0_ & 4095;                   // seq pos
        s16x4 pk;
#pragma unroll
        for (int rr = 0; rr < 4; ++rr) pk[rr] = f2bf(acc[mf][nf][rr] + bb);
        *(s16x4*)(vtp + ((size_t)(bI * Hn + hh) * Hd + dd) * Sq + s0) = pk;
      }
    } else {
#pragma unroll
      for (int mf = 0; mf < 4; ++mf) {
#pragma unroll
        for (int rr = 0; rr < 4; ++rr) {
          const int row = rowbase + mf * 16 + lg * 4 + rr;
          const float vv = acc[mf][nf][rr] + bb;
          if constexpr (OUT_BF16) {
            ((short*)C)[(size_t)row * ldC + col] = f2bf(vv);
          } else {
            ((float*)C)[(size_t)row * ldC + col] =
                vv + resid[(size_t)row * 768 + col];
          }
        }
      }
    }
  }
}

// ---------------------------------------------------------------------------
// Flash attention, bf16 MFMA 16x16x32, SWAPPED QK^T (S^T = K·Q^T).
// Structure = round-8 verbatim (reg-staged single-buffer, 2 barriers/tile,
// per-lane psum + lrow + shuffle epilogue — known good at 216 µs).
// SINGLE new change: defer-max (T13) — skip the O/l rescale unless some
// row's max grew by > 8 in log2 domain (P then bounded by 2^8).
// ---------------------------------------------------------------------------
__global__ __launch_bounds__(256) void attn_mfma_kernel(
    const short* __restrict__ qg, const short* __restrict__ kg,
    const short* __restrict__ vt, short* __restrict__ o) {
  __shared__ short Ks[64 * 64];     // [kv][d] swizzled
  __shared__ short Vs[64 * 64];     // [d][kv] swizzled
  __shared__ short Ps[4][16 * 64];  // wave-private [q][kv] swizzled
  const int q0 = blockIdx.x * 64;
  const int h = blockIdx.y, b = blockIdx.z;
  const size_t qkbase = ((size_t)b * Sq) * LDQKV + (size_t)h * Hd;
  const size_t vbase = ((size_t)(b * Hn + h) * Hd) * Sq;
  const size_t obase = ((size_t)b * Sq) * Dm + (size_t)h * Hd;
  const int t = threadIdx.x;
  const int w = t >> 6, l = t & 63;
  const int lr = l & 15, lg = l >> 4;

  // Q fragments (B-operand of swapped QK^T), hoisted
  bf16x8 aq0, aq1;
  {
    const short* qp = qg + qkbase + (size_t)(q0 + w * 16 + lr) * LDQKV + lg * 8;
    aq0 = *(const bf16x8*)qp;
    aq1 = *(const bf16x8*)(qp + 32);
  }

  float mrow = -INFINITY;  // running max for q = lr (log2 domain)
  float lrow = 0.f;        // per-lane PARTIAL denominator for q = lr
  f32x4 oacc[4] = {};      // lane: q = lg*4+r, d = nt*16+lr

  constexpr float SC = 0.18033688011112042f;  // (1/8) * log2(e)

  const int srow = t >> 3, sslot = t & 7;
  const int srow1 = srow + 32;

  // prefetch tile 0 into registers
  bf16x8 kreg0 = *(const bf16x8*)(kg + qkbase + (size_t)srow * LDQKV + sslot * 8);
  bf16x8 kreg1 = *(const bf16x8*)(kg + qkbase + (size_t)srow1 * LDQKV + sslot * 8);
  bf16x8 vreg0 = *(const bf16x8*)(vt + vbase + (size_t)srow * Sq + sslot * 8);
  bf16x8 vreg1 = *(const bf16x8*)(vt + vbase + (size_t)srow1 * Sq + sslot * 8);

  for (int kt = 0; kt < Sq; kt += 64) {
    __syncthreads();  // prior step's frag reads complete
    *(bf16x8*)&Ks[srow * 64 + ((sslot ^ (srow & 7)) * 8)] = kreg0;
    *(bf16x8*)&Ks[srow1 * 64 + ((sslot ^ (srow1 & 7)) * 8)] = kreg1;
    *(bf16x8*)&Vs[srow * 64 + ((sslot ^ (srow & 7)) * 8)] = vreg0;
    *(bf16x8*)&Vs[srow1 * 64 + ((sslot ^ (srow1 & 7)) * 8)] = vreg1;
    __syncthreads();

    // issue next tile's loads now; latency hides under this tile's math
    if (kt + 64 < Sq) {
      const int ktn = kt + 64;
      kreg0 = *(const bf16x8*)(kg + qkbase + (size_t)(ktn + srow) * LDQKV + sslot * 8);
      kreg1 = *(const bf16x8*)(kg + qkbase + (size_t)(ktn + srow1) * LDQKV + sslot * 8);
      vreg0 = *(const bf16x8*)(vt + vbase + (size_t)srow * Sq + ktn + sslot * 8);
      vreg1 = *(const bf16x8*)(vt + vbase + (size_t)srow1 * Sq + ktn + sslot * 8);
    }

    // S^T = K Q^T : s[nt][r] = S[kv = nt*16+lg*4+r][q = lr]
    f32x4 s[4];
    __builtin_amdgcn_s_setprio(1);
#pragma unroll
    for (int nt = 0; nt < 4; ++nt) {
      const int jr = nt * 16 + lr;
      const bf16x8 k0 = *(const bf16x8*)&Ks[jr * 64 + ((lg ^ (jr & 7)) * 8)];
      const bf16x8 k1 = *(const bf16x8*)&Ks[jr * 64 + (((4 + lg) ^ (jr & 7)) * 8)];
      f32x4 acc = {};
      acc = __builtin_amdgcn_mfma_f32_16x16x32_bf16(k0, aq0, acc, 0, 0, 0);
      acc = __builtin_amdgcn_mfma_f32_16x16x32_bf16(k1, aq1, acc, 0, 0, 0);
      s[nt] = acc;
    }
    __builtin_amdgcn_s_setprio(0);

    // row max (max3-shaped tree) + 2 cross-lane steps
    const float a0 = fmaxf(fmaxf(s[0][0], s[0][1]), s[0][2]);
    const float a1 = fmaxf(fmaxf(s[0][3], s[1][0]), s[1][1]);
    const float a2 = fmaxf(fmaxf(s[1][2], s[1][3]), s[2][0]);
    const float a3 = fmaxf(fmaxf(s[2][1], s[2][2]), s[2][3]);
    const float a4 = fmaxf(fmaxf(s[3][0], s[3][1]), s[3][2]);
    float tm = fmaxf(fmaxf(fmaxf(a0, a1), fmaxf(a2, a3)), fmaxf(a4, s[3][3]));
    tm = fmaxf(tm, __shfl_xor(tm, 16));
    tm = fmaxf(tm, __shfl_xor(tm, 32));
    const float tms = tm * SC;

    // defer-max (T13): rescale only when some row's max grew by > 8 (log2).
    // Wave-uniform branch (__all). When skipped, P <= 2^8 — safe in fp32/bf16;
    // numerator (oacc) and denominator (lrow) stay consistent w.r.t. mrow.
    if (!__all(tms - mrow <= 8.0f)) {
      const float mn = fmaxf(mrow, tms);
      const float esc = __builtin_amdgcn_exp2f(mrow - mn);
      mrow = mn;
      lrow *= esc;
      float escq[4];
#pragma unroll
      for (int r = 0; r < 4; ++r) escq[r] = __shfl(esc, lg * 4 + r);
#pragma unroll
      for (int nt = 0; nt < 4; ++nt)
#pragma unroll
        for (int r = 0; r < 4; ++r) oacc[nt][r] *= escq[r];
    }

    // P = exp2(S*SC - mrow); accumulate per-lane partial denominator
    const float negmn = -mrow;
    float psum = 0.f;
#pragma unroll
    for (int nt = 0; nt < 4; ++nt)
#pragma unroll
      for (int r = 0; r < 4; ++r) {
        const float p = __builtin_amdgcn_exp2f(fmaf(s[nt][r], SC, negmn));
        s[nt][r] = p;
        psum += p;
      }
    lrow += psum;  // partial over this lane's kv quarter

    // P pack: r-pairs are kv-adjacent -> cvt_pk + one b64 write per nt
#pragma unroll
    for (int nt = 0; nt < 4; ++nt) {
      uint2 pk;
      pk.x = cvt_pk_bf16(s[nt][0], s[nt][1]);
      pk.y = cvt_pk_bf16(s[nt][2], s[nt][3]);
      const int pslot = (nt * 2 + (lg >> 1)) ^ (lr & 7);
      *(uint2*)&Ps[w][lr * 64 + pslot * 8 + (lg & 1) * 4] = pk;
    }
    const bf16x8 ap0 = *(const bf16x8*)&Ps[w][lr * 64 + ((lg ^ (lr & 7)) * 8)];
    const bf16x8 ap1 = *(const bf16x8*)&Ps[w][lr * 64 + (((4 + lg) ^ (lr & 7)) * 8)];

    // O += P V
    __builtin_amdgcn_s_setprio(1);
#pragma unroll
    for (int nt = 0; nt < 4; ++nt) {
      const int dr = nt * 16 + lr;
      const bf16x8 b0 = *(const bf16x8*)&Vs[dr * 64 + ((lg ^ (dr & 7)) * 8)];
      const bf16x8 b1 = *(const bf16x8*)&Vs[dr * 64 + (((4 + lg) ^ (dr & 7)) * 8)];
      oacc[nt] = __builtin_amdgcn_mfma_f32_16x16x32_bf16(ap0, b0, oacc[nt], 0, 0, 0);
      oacc[nt] = __builtin_amdgcn_mfma_f32_16x16x32_bf16(ap1, b1, oacc[nt], 0, 0, 0);
    }
    __builtin_amdgcn_s_setprio(0);
  }

  // epilogue: reduce l across kv-quarter lanes, broadcast inv, write bf16
  float lt = lrow + __shfl_xor(lrow, 16);
  lt += __shfl_xor(lt, 32);
  const float inv = 1.0f / lt;  // valid per lane for q = lr
  float invq[4];
#pragma unroll
  for (int r = 0; r < 4; ++r) invq[r] = __shfl(inv, lg * 4 + r);
#pragma unroll
  for (int r = 0; r < 4; ++r) {
    short* orow = o + obase + (size_t)(q0 + w * 16 + lg * 4 + r) * Dm;
#pragma unroll
    for (int nt = 0; nt < 4; ++nt)
      orow[nt * 16 + lr] = f2bf(oacc[nt][r] * invq[r]);
  }
}

// ---------------------------------------------------------------------------
extern "C" void kernel_launch(void* const* d_in, const int* in_sizes, int n_in,
                              void* d_out, int out_size, void* d_ws, size_t ws_size,
                              hipStream_t stream) {
  (void)in_sizes; (void)n_in; (void)out_size; (void)ws_size;
  const float* x  = (const float*)d_in[0];
  const float* Wq = (const float*)d_in[1];
  const float* bq = (const float*)d_in[2];
  const float* Wk = (const float*)d_in[3];
  const float* bk = (const float*)d_in[4];
  const float* Wv = (const float*)d_in[5];
  const float* bv = (const float*)d_in[6];
  const float* Wo = (const float*)d_in[7];
  const float* bo = (const float*)d_in[8];
  const float* lg = (const float*)d_in[9];
  const float* lb = (const float*)d_in[10];
  float* out = (float*)d_out;

  const size_t n = (size_t)Mrows * Dm;
  short* ws16 = (short*)d_ws;
  short* xn   = ws16;                             // bf16 LN out      [M][768]
  short* qkv  = xn + n;                           // bf16 QK(+V slot) [M][2304]
  short* vt   = qkv + (size_t)Mrows * LDQKV;      // bf16 V^T         [B,H,64,S]
  short* ab   = vt + n;                           // bf16 attn out    [M][768]
  short* Wt   = ab + n;                           // bf16 weights^T   [3072][768]
  float* ball = (float*)(Wt + (size_t)3072 * 768);  // f32 bias      [3072]

  wprep_kernel<<<dim3(12, 12, 4), 256, 0, stream>>>(Wq, Wk, Wv, Wo, Wt);
  biaspack_kernel<<<12, 256, 0, stream>>>(bq, bk, bv, bo, ball);
  ln_kernel<<<Mrows, 256, 0, stream>>>(x, lg, lb, xn);
  gemm128_kernel<true, false, true><<<dim3(Mrows / 128, LDQKV / 128), 256, 0, stream>>>(
      xn, Dm, Wt, ball, nullptr, qkv, LDQKV, vt);
  attn_mfma_kernel<<<dim3(Sq / 64, Hn, Bz), 256, 0, stream>>>(qkv, qkv + 768, vt, ab);
  gemm128_kernel<false, true, false><<<dim3(Mrows / 128, Dm / 128), 256, 0, stream>>>(
      ab, Dm, Wt + (size_t)2304 * 768, ball + 2304, x, out, Dm, nullptr);
}